// Round 7
// baseline (572.972 us; speedup 1.0000x reference)
//
#include <hip/hip_runtime.h>
#include <math.h>

#define N    257     // state dim
#define AP   258     // doubles per A row (cols 0..256 = S, col 257 = rhs)
#define MM   128     // rotation pairs
#define LL   512     // seq length
#define BB   4       // batch
#define NB   32      // panel width
#define UDS  227     // U12 LDS row stride

// ws byte layout:
#define A_BYTE    0         // double[257*258] = 530448
#define W0_BYTE   530448    // float[257]
#define CXY_BYTE  531488    // float[4096]
#define PW_BYTE   547904    // double[32*257] = 65792
#define U12_BYTE  613696    // double[32*226] = 57856

// ---------------------------------------------------------------------------
// prefix sums of x[b,:,comp]: theta[b,l,m] = cx[b,l]*om0[m] + cy[b,l]*om1[m]
// ---------------------------------------------------------------------------
__global__ __launch_bounds__(512) void scan_kernel(const float* __restrict__ x,
                                                   void* __restrict__ wsv) {
  const int tid  = threadIdx.x;
  const int wave = tid >> 6, lane = tid & 63;
  const int b    = wave >> 1, comp = wave & 1;

  const float* xp = x + ((size_t)b * LL) * 2 + comp;
  double loc[8];
  double run = 0.0;
  #pragma unroll
  for (int e = 0; e < 8; ++e) {
    run += (double)xp[(lane * 8 + e) * 2];
    loc[e] = run;
  }
  double tot = run;
  #pragma unroll
  for (int off = 1; off < 64; off <<= 1) {
    const double o = __shfl_up(tot, off);
    if (lane >= off) tot += o;
  }
  const double excl = tot - run;
  float* cp = (float*)((char*)wsv + CXY_BYTE) + ((size_t)b * LL) * 2 + comp;
  #pragma unroll
  for (int e = 0; e < 8; ++e)
    cp[(lane * 8 + e) * 2] = (float)(excl + loc[e]);
}

// ---------------------------------------------------------------------------
// stage A = [S | z0] in fp64, grid-wide
// ---------------------------------------------------------------------------
__global__ __launch_bounds__(256) void stage_kernel(const float* __restrict__ S,
                                                    const float* __restrict__ z0,
                                                    void* __restrict__ wsv) {
  double* A = (double*)((char*)wsv + A_BYTE);
  const int idx = blockIdx.x * 256 + threadIdx.x;
  if (idx < N * N) {
    const int i = idx / N, j = idx - i * N;
    A[i * AP + j] = (double)S[idx];
  } else {
    const int r = idx - N * N;
    if (r < N) A[r * AP + N] = (double)z0[r];
  }
}

// ---------------------------------------------------------------------------
// panel factor (1 block, 512 thr) — ARRAY-FREE (all state in LDS, no scratch).
//  - Pnl: panel cols k0..k0+31 for ALL 257 rows, column-major (stride 257).
//  - In-panel elimination, 32 sequential steps. At step j, thread tid owns
//    row tid; eliminate every row EXCEPT pivot rows k0..k0+j. This yields:
//      rows < k0      : M01 = A01 U11^-1   (forward-subst identity)
//      rows > k0+j    : L multipliers      (standard GE)
//      pivot rows     : U11 upper triangle + L mults below diag
//    — exactly the semantics verified in rounds 3-6.
//  - U12 = L11^-1 A12 per-column in LDS (column-private, no barriers).
// ---------------------------------------------------------------------------
__global__ __launch_bounds__(512) void panel_factor_kernel(void* __restrict__ wsv,
                                                           int k0) {
  __shared__ double Pnl[NB * N];     // [c*257 + row]  = 65792 B
  __shared__ double U12[NB * UDS];   // [jr*227 + c]   = 58112 B
  double* A    = (double*)((char*)wsv + A_BYTE);
  double* Pw   = (double*)((char*)wsv + PW_BYTE);
  double* U12w = (double*)((char*)wsv + U12_BYTE);
  const int tid = threadIdx.x;
  const int ct  = k0 + NB;
  const int tc2 = 258 - ct;          // trailing cols incl rhs

  // load panel (global coalesced: 32 consecutive doubles per row)
  for (int idx = tid; idx < N * NB; idx += 512) {
    const int i = idx >> 5, c = idx & 31;
    Pnl[c * N + i] = A[i * AP + k0 + c];
  }
  // stage pivot rows' trailing block (incl rhs)
  for (int idx = tid; idx < NB * tc2; idx += 512) {
    const int jr = idx / tc2, c = idx - jr * tc2;
    U12[jr * UDS + c] = A[(k0 + jr) * AP + ct + c];
  }
  __syncthreads();

  // in-panel elimination: 32 sequential steps
  for (int j = 0; j < NB; ++j) {
    const int prow = k0 + j;
    const double pinv = 1.0 / Pnl[j * N + prow];   // broadcast read
    if (tid < N && (tid < k0 || tid > prow)) {
      const double m = Pnl[j * N + tid] * pinv;
      Pnl[j * N + tid] = m;
      for (int c = j + 1; c < NB; ++c)
        Pnl[c * N + tid] -= m * Pnl[c * N + prow];
    }
    __syncthreads();
  }

  // U12 = L11^-1 * A12, column-private sequential (no barriers needed)
  if (tid < tc2) {
    for (int jr = 1; jr < NB; ++jr) {
      double acc = U12[jr * UDS + tid];
      for (int t = 0; t < jr; ++t)
        acc -= Pnl[t * N + (k0 + jr)] * U12[t * UDS + tid];
      U12[jr * UDS + tid] = acc;
    }
  }
  __syncthreads();

  // write back:
  // 1) pivot rows' panel (U11 + L mults) -> A (for finish_kernel)
  for (int idx = tid; idx < NB * NB; idx += 512) {
    const int jr = idx >> 5, c = idx & 31;
    A[(k0 + jr) * AP + (k0 + c)] = Pnl[c * N + (k0 + jr)];
  }
  // 2) U12 -> A pivot trailing (incl rhs) + compact U12w for update kernels
  for (int idx = tid; idx < NB * tc2; idx += 512) {
    const int jr = idx / tc2, c = idx - jr * tc2;
    const double v = U12[jr * UDS + c];
    A[(k0 + jr) * AP + ct + c] = v;
    U12w[jr * 226 + c] = v;
  }
  // 3) multipliers -> Pw transposed [c*N + row] (pivot-row values unused,
  //    written anyway for coalescing simplicity)
  for (int idx = tid; idx < NB * N; idx += 512) {
    const int c = idx / N, i = idx - c * N;
    Pw[c * N + i] = Pnl[c * N + i];
  }
}

// ---------------------------------------------------------------------------
// panel update (grid-parallel Jordan rank-32 GEMM):
//   rows R = [0,k0) U [ct,N), cols [ct,258): A[gr][c] -= sum_t Pw[t][gr]*U12[t][c]
// ---------------------------------------------------------------------------
__global__ __launch_bounds__(256) void panel_update_kernel(void* __restrict__ wsv,
                                                           int k0, int tc2) {
  __shared__ double Pl[NB][NB + 1];
  __shared__ __align__(16) double Ul[NB][66];
  double* A = (double*)((char*)wsv + A_BYTE);
  const double* Pw   = (const double*)((const char*)wsv + PW_BYTE);
  const double* U12w = (const double*)((const char*)wsv + U12_BYTE);
  const int tid = threadIdx.x;
  const int ct  = k0 + NB;
  const int rb0 = blockIdx.x * 32;
  const int c0  = blockIdx.y * 64;

  for (int i = tid; i < 32 * 32; i += 256) {
    const int t = i >> 5, rr = i & 31;
    const int rb = rb0 + rr;
    const int gr = (rb < k0) ? rb : rb + NB;
    Pl[t][rr] = (rb < 225) ? Pw[t * N + gr] : 0.0;
  }
  for (int i = tid; i < 32 * 64; i += 256) {
    const int t = i >> 6, c = i & 63;
    Ul[t][c] = (c0 + c < tc2) ? U12w[t * 226 + c0 + c] : 0.0;
  }
  __syncthreads();

  const int tr  = tid >> 4;
  const int tcx = (tid & 15) * 4;
  double acc[2][4];
  #pragma unroll
  for (int rr = 0; rr < 2; ++rr) {
    const int rb = rb0 + tr * 2 + rr;
    const int gr = (rb < k0) ? rb : rb + NB;
    #pragma unroll
    for (int c = 0; c < 4; ++c)
      acc[rr][c] = (rb < 225 && (c0 + tcx + c) < tc2)
                 ? A[gr * AP + ct + c0 + tcx + c] : 0.0;
  }
  #pragma unroll
  for (int t = 0; t < NB; ++t) {
    const double p0 = Pl[t][tr * 2], p1 = Pl[t][tr * 2 + 1];
    const double2 u0 = *(const double2*)&Ul[t][tcx];
    const double2 u1 = *(const double2*)&Ul[t][tcx + 2];
    acc[0][0] -= p0 * u0.x; acc[0][1] -= p0 * u0.y;
    acc[0][2] -= p0 * u1.x; acc[0][3] -= p0 * u1.y;
    acc[1][0] -= p1 * u0.x; acc[1][1] -= p1 * u0.y;
    acc[1][2] -= p1 * u1.x; acc[1][3] -= p1 * u1.y;
  }
  #pragma unroll
  for (int rr = 0; rr < 2; ++rr) {
    const int rb = rb0 + tr * 2 + rr;
    const int gr = (rb < k0) ? rb : rb + NB;
    #pragma unroll
    for (int c = 0; c < 4; ++c)
      if (rb < 225 && (c0 + tcx + c) < tc2)
        A[gr * AP + ct + c0 + tcx + c] = acc[rr][c];
  }
}

// ---------------------------------------------------------------------------
// finish: x256 division, then 8 independent per-panel 32-step back-substs
// ---------------------------------------------------------------------------
__global__ __launch_bounds__(256) void finish_kernel(void* __restrict__ wsv) {
  __shared__ double xs[N];
  __shared__ double rr[256];
  double* A   = (double*)((char*)wsv + A_BYTE);
  float*  w0f = (float*)((char*)wsv + W0_BYTE);
  const int tid = threadIdx.x;
  if (tid == 0) xs[256] = A[256 * AP + 257] / A[256 * AP + 256];
  __syncthreads();
  const double x256 = xs[256];
  rr[tid] = A[tid * AP + 257] - A[tid * AP + 256] * x256;
  __syncthreads();
  const int fk0 = tid & ~31;
  const int fs  = tid & 31;
  for (int j = 31; j >= 0; --j) {
    if (fs == j) xs[fk0 + j] = rr[fk0 + j] / A[(fk0 + j) * AP + (fk0 + j)];
    __syncthreads();
    if (fs < j) rr[fk0 + fs] -= A[(fk0 + fs) * AP + (fk0 + j)] * xs[fk0 + j];
    __syncthreads();
  }
  w0f[tid] = (float)xs[tid];
  if (tid == 0) w0f[256] = (float)xs[256];
}

// ---------------------------------------------------------------------------
// combine: out[(b,l), i] = sum_d S[i,d] * W[(b,l), d]
// ---------------------------------------------------------------------------
#define NL 8
__global__ __launch_bounds__(320) void combine_kernel(const float* __restrict__ S,
                                                      const float* __restrict__ om,
                                                      const void* __restrict__ wsv,
                                                      float* __restrict__ out) {
  const int tid = threadIdx.x;
  const int b  = blockIdx.y;
  const int l0 = blockIdx.x * NL;
  const float* w0  = (const float*)((const char*)wsv + W0_BYTE);
  const float* cxy = (const float*)((const char*)wsv + CXY_BYTE);
  __shared__ float Wl[NL][N];
  __shared__ float omsh[2 * MM];
  __shared__ float cxs[NL], cys[NL];

  for (int idx = tid; idx < 2 * MM; idx += 320) omsh[idx] = om[idx];
  if (tid < NL) {
    cxs[tid] = cxy[((size_t)(b * LL) + l0 + tid) * 2];
    cys[tid] = cxy[((size_t)(b * LL) + l0 + tid) * 2 + 1];
  }
  __syncthreads();

  for (int idx = tid; idx < NL * N; idx += 320) {
    const int r = idx / N;
    const int d = idx - r * N;
    float v;
    if (d == 0) {
      v = w0[0];
    } else {
      const int m = (d - 1) >> 1;
      const int pq = 2 * m + 1;
      const float t = cxs[r] * omsh[2 * m] + cys[r] * omsh[2 * m + 1];
      float s, c;
      sincosf(t, &s, &c);
      const float a0 = w0[pq], a1 = w0[pq + 1];
      v = (d & 1) ? (c * a0 - s * a1) : (s * a0 + c * a1);
    }
    Wl[r][d] = v;
  }
  __syncthreads();

  const int i = tid;
  if (i < N) {
    const float* Si = S + (size_t)i * N;
    float acc[NL];
    #pragma unroll
    for (int r = 0; r < NL; ++r) acc[r] = 0.0f;
    #pragma unroll 4
    for (int d = 0; d < N; ++d) {
      const float sv = Si[d];
      #pragma unroll
      for (int r = 0; r < NL; ++r) acc[r] += sv * Wl[r][d];
    }
    const size_t base = (size_t)(b * LL + l0) * N + i;
    #pragma unroll
    for (int r = 0; r < NL; ++r) out[base + (size_t)r * N] = acc[r];
    if (l0 + NL == LL) {
      out[(size_t)BB * LL * N + (size_t)b * N + i] = acc[NL - 1];
    }
  }
}

extern "C" void kernel_launch(void* const* d_in, const int* in_sizes, int n_in,
                              void* d_out, int out_size, void* d_ws, size_t ws_size,
                              hipStream_t stream) {
  const float* x  = (const float*)d_in[0];   // (B, L, 2)
  const float* z0 = (const float*)d_in[1];   // (D,)
  const float* om = (const float*)d_in[2];   // (M, 2)
  const float* S  = (const float*)d_in[3];   // (D, D)
  float* out = (float*)d_out;                // outputs (B,L,D) then z_final (B,D)

  hipLaunchKernelGGL(scan_kernel,  dim3(1),   dim3(512), 0, stream, x, d_ws);
  hipLaunchKernelGGL(stage_kernel, dim3(260), dim3(256), 0, stream, S, z0, d_ws);
  for (int p = 0; p < 8; ++p) {
    const int k0  = p * NB;
    const int tc2 = 258 - (k0 + NB);
    hipLaunchKernelGGL(panel_factor_kernel, dim3(1), dim3(512), 0, stream, d_ws, k0);
    hipLaunchKernelGGL(panel_update_kernel, dim3(8, (tc2 + 63) / 64), dim3(256),
                       0, stream, d_ws, k0, tc2);
  }
  hipLaunchKernelGGL(finish_kernel, dim3(1), dim3(256), 0, stream, d_ws);
  hipLaunchKernelGGL(combine_kernel, dim3(LL / NL, BB), dim3(320), 0, stream, S, om, d_ws, out);
}